// Round 14
// baseline (20.584 us; speedup 1.0000x reference)
//
#include <hip/hip_runtime.h>
#include <hip/hip_bf16.h>

#define N_SHARD 4
#define PPP     512
#define NEG_N   1024
#define EMB     256
#define NROWS   (N_SHARD * PPP)   // 2048

typedef __attribute__((ext_vector_type(8))) short bf16x8;  // 8 bf16 (4 VGPRs)
typedef __attribute__((ext_vector_type(4))) float f32x4;   // 4 fp32 acc

__device__ __forceinline__ unsigned short f2bf(float f) {
    union { float f; unsigned int u; } v; v.f = f;
    return (unsigned short)((v.u + 0x7FFFu + ((v.u >> 16) & 1u)) >> 16);
}

// ONE kernel, no workspace, no cross-block dependency. Grid 256 x 512 threads.
// Block (p = bx&31, q = bx>>5): output rows p*64..+64, col-pair q*128..+128
// (gather-optimal tile: minimize 4096/C + 2048/R s.t. RC=8192 -> 64x128).
// bx%8 == p%8 -> all 8 q-blocks sharing an A-panel live on one XCD.
// r14 change vs r10: PLAIN stores instead of nontemporal. During the timed
// replay loop nothing else touches memory, so the ~40 MB live set (5 MB
// gathered rows + 33.5 MB output) is L2/L3-resident in steady state; NT
// stores were forcing 33.5 MB to HBM every replay for no benefit.
__global__ __launch_bounds__(512, 1) void fused_kernel(
    const int* __restrict__ head, const int* __restrict__ relation,
    const int* __restrict__ tail, const int* __restrict__ negative,
    const float* __restrict__ ent, const float* __restrict__ relemb,
    float* __restrict__ pos_out, float* __restrict__ neg_out)
{
    __shared__ unsigned short Abuf[64 * EMB];    // 32 KiB, XOR-swizzled
    __shared__ unsigned short Bbuf[128 * EMB];   // 64 KiB, XOR-swizzled
    __shared__ int idxbuf[64 * 3 + 128];         // 1.25 KiB

    const int tid  = threadIdx.x;
    const int wid  = tid >> 6;        // 0..7
    const int lane = tid & 63;
    const int p    = blockIdx.x & 31;
    const int q    = blockIdx.x >> 5; // 0..7
    const int row0 = p * 64;
    const int colp = q * 128;

    int* hIdx = idxbuf;               // 64
    int* rIdx = idxbuf + 64;          // 64
    int* tIdx = idxbuf + 128;         // 64 (q==0 only)
    int* nIdx = idxbuf + 192;         // 128

    // ---- Phase 0: coalesced index preload ----
    if (tid < 64)            hIdx[tid]       = head[row0 + tid];
    else if (tid < 128)      rIdx[tid - 64]  = relation[row0 + tid - 64];
    else if (tid < 256)      nIdx[tid - 128] = negative[colp + tid - 128]; // shard 0
    else if (tid < 320 && q == 0) tIdx[tid - 256] = tail[row0 + tid - 256];
    __syncthreads();

    // ---- Phase 1: A gather (wave w -> rows w*8..+8), hr -> bf16 LDS ----
    #pragma unroll
    for (int i = 0; i < 8; ++i) {
        const int r = wid * 8 + i;
        const float4 h4 = ((const float4*)(ent    + (size_t)hIdx[r] * EMB))[lane];
        const float4 r4 = ((const float4*)(relemb + (size_t)rIdx[r] * EMB))[lane];
        const float x = h4.x * r4.x, y = h4.y * r4.y;
        const float z = h4.z * r4.z, w = h4.w * r4.w;
        const ushort4 s = make_ushort4(f2bf(x), f2bf(y), f2bf(z), f2bf(w));
        *(ushort4*)((char*)Abuf + r * 512 + ((lane * 8) ^ ((r & 7) << 4))) = s;
        if (q == 0) {
            const float4 t4 = ((const float4*)(ent + (size_t)tIdx[r] * EMB))[lane];
            float pd = x * t4.x + y * t4.y + z * t4.z + w * t4.w;
            #pragma unroll
            for (int off = 32; off > 0; off >>= 1) pd += __shfl_down(pd, off, 64);
            if (lane == 0) pos_out[row0 + r] = pd;
        }
    }
    // ---- Phase 1b: B gather (wave w -> rows w*16..+16) ----
    #pragma unroll
    for (int i = 0; i < 16; ++i) {
        const int m = wid * 16 + i;
        const float4 t4 = ((const float4*)(ent + (size_t)nIdx[m] * EMB))[lane];
        const ushort4 s = make_ushort4(f2bf(t4.x), f2bf(t4.y), f2bf(t4.z), f2bf(t4.w));
        *(ushort4*)((char*)Bbuf + m * 512 + ((lane * 8) ^ ((m & 7) << 4))) = s;
    }
    __syncthreads();

    // ---- Phase 2: MFMA. wave (wr = wid>>1, wc = wid&1): 16 rows x 64 cols ----
    const int r16  = lane & 15;
    const int half = lane >> 4;
    const int wr   = wid >> 1, wc = wid & 1;
    const int arow = wr * 16 + r16;
    const int aswz = (arow & 7) << 4;
    const int bb   = wc * 64;
    const int bswz = (r16 & 7) << 4;

    f32x4 acc[4];
    #pragma unroll
    for (int nf = 0; nf < 4; ++nf) acc[nf] = (f32x4){0.f, 0.f, 0.f, 0.f};

    #pragma unroll
    for (int kk = 0; kk < 8; ++kk) {
        const int koff = kk * 64 + half * 16;
        const bf16x8 a = *(const bf16x8*)((const char*)Abuf + arow * 512 + (koff ^ aswz));
        #pragma unroll
        for (int nf = 0; nf < 4; ++nf) {
            const bf16x8 b = *(const bf16x8*)((const char*)Bbuf + (bb + nf * 16 + r16) * 512 + (koff ^ bswz));
            acc[nf] = __builtin_amdgcn_mfma_f32_16x16x32_bf16(a, b, acc[nf], 0, 0, 0);
        }
    }
    __syncthreads();   // A-rows are read by TWO col-waves: all MFMAs done before scratch reuse

    // ---- Epilogue: intra-wave LDS transpose (4KB scratch slice per wave in
    //      the dead A-buf), then coalesced PLAIN float4 stores x4 replicas ----
    float* cw = (float*)((char*)Abuf + wid * 4096);
    #pragma unroll
    for (int v = 0; v < 4; ++v) {
        const int lr = half * 4 + v;
        #pragma unroll
        for (int nf = 0; nf < 4; ++nf) {
            const int c = nf * 16 + r16;
            cw[lr * 64 + (c ^ (half << 4))] = acc[nf][v];
        }
    }
    #pragma unroll
    for (int j = 0; j < 4; ++j) {
        const int lr = j * 4 + half;
        const f32x4 v4 = *(const f32x4*)&cw[lr * 64 + ((r16 * 4) ^ (j << 4))];
        const int grow = row0 + wr * 16 + lr;
        float* orow = neg_out + (size_t)grow * 4096 + colp + wc * 64 + r16 * 4;
        *(f32x4*)(orow)        = v4;
        *(f32x4*)(orow + 1024) = v4;
        *(f32x4*)(orow + 2048) = v4;
        *(f32x4*)(orow + 3072) = v4;
    }
}

extern "C" void kernel_launch(void* const* d_in, const int* in_sizes, int n_in,
                              void* d_out, int out_size, void* d_ws, size_t ws_size,
                              hipStream_t stream) {
    const int*   head     = (const int*)d_in[0];
    const int*   relation = (const int*)d_in[1];
    const int*   tail     = (const int*)d_in[2];
    const int*   negative = (const int*)d_in[3];
    const float* ent      = (const float*)d_in[4];
    const float* rel      = (const float*)d_in[5];

    float* pos_out = (float*)d_out;            // 2048
    float* neg_out = (float*)d_out + NROWS;    // 2048 * 4096

    fused_kernel<<<256, 512, 0, stream>>>(head, relation, tail, negative,
                                          ent, rel, pos_out, neg_out);
}

// Round 15
// 18.104 us; speedup vs baseline: 1.1369x; 1.1369x over previous
//
#include <hip/hip_runtime.h>
#include <hip/hip_bf16.h>

#define N_SHARD 4
#define PPP     512
#define NEG_N   1024
#define EMB     256
#define NROWS   (N_SHARD * PPP)   // 2048

typedef __attribute__((ext_vector_type(8))) short bf16x8;  // 8 bf16 (4 VGPRs)
typedef __attribute__((ext_vector_type(4))) float f32x4;   // 4 fp32 acc

__device__ __forceinline__ unsigned short f2bf(float f) {
    union { float f; unsigned int u; } v; v.f = f;
    return (unsigned short)((v.u + 0x7FFFu + ((v.u >> 16) & 1u)) >> 16);
}

// FINAL (r10 verbatim, measured optimum 18.2 us):
// ONE kernel, no workspace, no cross-block dependency. Grid 256 x 512 threads.
// Block (p = bx&31, q = bx>>5): output rows p*64..+64, col-pair q*128..+128
// (gather-optimal tile: minimize 4096/C + 2048/R s.t. RC=8192 -> 64x128).
// bx%8 == p%8 -> all 8 q-blocks sharing an A-panel live on one XCD.
// NT stores are required (+2.4 us if plain: write-allocate pollutes L2 and
// evicts the gather working set — r14 ablation).
// Byte model: (64 MB gather + 33.5 MB NT writes)/~6.8 TB/s + ~3 us fixed.
// Cross-block byte-sharing is closed on this stack: intra-kernel ws
// producer->consumer is never visible across blocks (r6-r9, 4 sync variants);
// two-kernel staging pays kernel-boundary L2 writeback and ties (r12).
__global__ __launch_bounds__(512, 1) void fused_kernel(
    const int* __restrict__ head, const int* __restrict__ relation,
    const int* __restrict__ tail, const int* __restrict__ negative,
    const float* __restrict__ ent, const float* __restrict__ relemb,
    float* __restrict__ pos_out, float* __restrict__ neg_out)
{
    __shared__ unsigned short Abuf[64 * EMB];    // 32 KiB, XOR-swizzled
    __shared__ unsigned short Bbuf[128 * EMB];   // 64 KiB, XOR-swizzled
    __shared__ int idxbuf[64 * 3 + 128];         // 1.25 KiB

    const int tid  = threadIdx.x;
    const int wid  = tid >> 6;        // 0..7
    const int lane = tid & 63;
    const int p    = blockIdx.x & 31;
    const int q    = blockIdx.x >> 5; // 0..7
    const int row0 = p * 64;
    const int colp = q * 128;

    int* hIdx = idxbuf;               // 64
    int* rIdx = idxbuf + 64;          // 64
    int* tIdx = idxbuf + 128;         // 64 (q==0 only)
    int* nIdx = idxbuf + 192;         // 128

    // ---- Phase 0: coalesced index preload (kills idx->row latency chains) ----
    if (tid < 64)            hIdx[tid]       = head[row0 + tid];
    else if (tid < 128)      rIdx[tid - 64]  = relation[row0 + tid - 64];
    else if (tid < 256)      nIdx[tid - 128] = negative[colp + tid - 128]; // shard 0
    else if (tid < 320 && q == 0) tIdx[tid - 256] = tail[row0 + tid - 256];
    __syncthreads();

    // ---- Phase 1: A gather (wave w -> rows w*8..+8). hr product -> bf16 LDS ----
    #pragma unroll
    for (int i = 0; i < 8; ++i) {
        const int r = wid * 8 + i;
        const float4 h4 = ((const float4*)(ent    + (size_t)hIdx[r] * EMB))[lane];
        const float4 r4 = ((const float4*)(relemb + (size_t)rIdx[r] * EMB))[lane];
        const float x = h4.x * r4.x, y = h4.y * r4.y;
        const float z = h4.z * r4.z, w = h4.w * r4.w;
        const ushort4 s = make_ushort4(f2bf(x), f2bf(y), f2bf(z), f2bf(w));
        *(ushort4*)((char*)Abuf + r * 512 + ((lane * 8) ^ ((r & 7) << 4))) = s;
        if (q == 0) {
            const float4 t4 = ((const float4*)(ent + (size_t)tIdx[r] * EMB))[lane];
            float pd = x * t4.x + y * t4.y + z * t4.z + w * t4.w;
            #pragma unroll
            for (int off = 32; off > 0; off >>= 1) pd += __shfl_down(pd, off, 64);
            if (lane == 0) pos_out[row0 + r] = pd;
        }
    }
    // ---- Phase 1b: B gather (wave w -> rows w*16..+16) ----
    #pragma unroll
    for (int i = 0; i < 16; ++i) {
        const int m = wid * 16 + i;
        const float4 t4 = ((const float4*)(ent + (size_t)nIdx[m] * EMB))[lane];
        const ushort4 s = make_ushort4(f2bf(t4.x), f2bf(t4.y), f2bf(t4.z), f2bf(t4.w));
        *(ushort4*)((char*)Bbuf + m * 512 + ((lane * 8) ^ ((m & 7) << 4))) = s;
    }
    __syncthreads();

    // ---- Phase 2: MFMA. wave (wr = wid>>1, wc = wid&1): 16 rows x 64 cols ----
    const int r16  = lane & 15;
    const int half = lane >> 4;
    const int wr   = wid >> 1, wc = wid & 1;
    const int arow = wr * 16 + r16;
    const int aswz = (arow & 7) << 4;
    const int bb   = wc * 64;                  // B row base; (bb+nf*16)%8 == 0
    const int bswz = (r16 & 7) << 4;

    f32x4 acc[4];
    #pragma unroll
    for (int nf = 0; nf < 4; ++nf) acc[nf] = (f32x4){0.f, 0.f, 0.f, 0.f};

    #pragma unroll
    for (int kk = 0; kk < 8; ++kk) {
        const int koff = kk * 64 + half * 16;
        const bf16x8 a = *(const bf16x8*)((const char*)Abuf + arow * 512 + (koff ^ aswz));
        #pragma unroll
        for (int nf = 0; nf < 4; ++nf) {
            const bf16x8 b = *(const bf16x8*)((const char*)Bbuf + (bb + nf * 16 + r16) * 512 + (koff ^ bswz));
            acc[nf] = __builtin_amdgcn_mfma_f32_16x16x32_bf16(a, b, acc[nf], 0, 0, 0);
        }
    }
    __syncthreads();   // A-rows are read by TWO col-waves: all MFMAs done before scratch reuse

    // ---- Epilogue: intra-wave LDS transpose (4KB scratch slice per wave in
    //      the dead A-buf), then coalesced NT float4 stores x4 replicas ----
    float* cw = (float*)((char*)Abuf + wid * 4096);
    #pragma unroll
    for (int v = 0; v < 4; ++v) {
        const int lr = half * 4 + v;
        #pragma unroll
        for (int nf = 0; nf < 4; ++nf) {
            const int c = nf * 16 + r16;
            cw[lr * 64 + (c ^ (half << 4))] = acc[nf][v];
        }
    }
    #pragma unroll
    for (int j = 0; j < 4; ++j) {
        const int lr = j * 4 + half;
        const f32x4 v4 = *(const f32x4*)&cw[lr * 64 + ((r16 * 4) ^ (j << 4))];
        const int grow = row0 + wr * 16 + lr;
        float* orow = neg_out + (size_t)grow * 4096 + colp + wc * 64 + r16 * 4;
        __builtin_nontemporal_store(v4, (f32x4*)(orow));
        __builtin_nontemporal_store(v4, (f32x4*)(orow + 1024));
        __builtin_nontemporal_store(v4, (f32x4*)(orow + 2048));
        __builtin_nontemporal_store(v4, (f32x4*)(orow + 3072));
    }
}

extern "C" void kernel_launch(void* const* d_in, const int* in_sizes, int n_in,
                              void* d_out, int out_size, void* d_ws, size_t ws_size,
                              hipStream_t stream) {
    const int*   head     = (const int*)d_in[0];
    const int*   relation = (const int*)d_in[1];
    const int*   tail     = (const int*)d_in[2];
    const int*   negative = (const int*)d_in[3];
    const float* ent      = (const float*)d_in[4];
    const float* rel      = (const float*)d_in[5];

    float* pos_out = (float*)d_out;            // 2048
    float* neg_out = (float*)d_out + NROWS;    // 2048 * 4096

    fused_kernel<<<256, 512, 0, stream>>>(head, relation, tail, negative,
                                          ent, rel, pos_out, neg_out);
}